// Round 12
// baseline (137.355 us; speedup 1.0000x reference)
//
#include <hip/hip_runtime.h>

// Dilated attention, [1, 8192, 8, 64] fp32 in/out.
// Group 0 (heads 0-3): 4 segments x 2048 tokens, rate 1, dense causal.
// Group 1 (heads 4-7): 1 segment, odd tokens only (4096 dilated), evens = 0.
//
// ===== R24: dual-subtile waves (128-thread blocks) on the R18 structure =====
// prep:    gather dilated tokens -> bf16 ws:
//            Kb[region][pos][64d]        (chunk-XOR-swizzled rows, for LDS)
//            Vt[region][kb][8chunk][64lane][8] (MFMA-frag order, reg-direct)
// attn:    64-query blocks, 2 waves x 32 q (subtiles w*16 and 32+w*16).
//          K double-buffered in 16KB LDS via global_load_lds, ONE
//          __syncthreads/iter; V global->register, SHARED by both subtiles;
//          K frag ds_reads SHARED by both subtiles -> per-q memory ops,
//          staging, and barriers all HALVE; each wave carries 2 independent
//          QK->exp2->pack->PV chains (ILP x2). No-max softmax; exp2 with
//          log2e folded into Q scale. S^T operand swap (R16): P in-register
//          via cvt_pk_bf16 + permlane swaps.
//          Group-1 tiles split into 2 K-chunks -> unnormalized partials to ws.
// combine: per group-1 tile, sum <=2 slots, divide, write odd tokens,
//          zero paired even tokens.
// Dispatch (R13, unchanged): CU c gets g1 chunk0+chunk1 of tile 63-(c>>2)
//          plus two g0 tiles tloc=c>>3 -> ~66 iters/CU; 2 LONG blocks/CU;
//          steady state 8 waves/CU (same as R23's measured plateau).
//
// Ledger (what NOT to retry):
// R5:  launch_bounds(256,8) VGPR spill. R6: scattered 16B frag reads 805MB.
// R7:  unswizzled ws rows = LDS conflicts. R10: fatter Q-BLOCKS regress.
// R12: ONE variable per round. R14/R19: more blocks/finer chunks never help;
//      occupancy counter never moves. R15 WIN: uniform causal branch.
// R16 WIN: S^T swap, P in-register. R17: counted-vmcnt LDS pipeline neutral.
// R18 WIN: V global->reg frag-order, LDS 16KB (config = 128.3us baseline).
// R20: k-pairing (2 kb/barrier, +LDS, +VGPR) regressed. R21: barrier-free
//      loses prefetch (compiler sinks loads). R22: forced reg double-buffer
//      half-serialized; worse. R23: revert confirmed 128.46us.
// R24 theory: 8 co-stalled waves/CU each ~700cy/iter chain; halve the
//      per-q overhead + double per-wave ILP at constant wave count.

#define LP 72

typedef __attribute__((ext_vector_type(8))) short bf16x8;
typedef __attribute__((ext_vector_type(4))) float f32x4;
typedef __attribute__((ext_vector_type(4))) unsigned u32x4;
typedef const unsigned int __attribute__((address_space(1)))* gp1;
typedef unsigned int __attribute__((address_space(3)))* lp3;

__device__ __forceinline__ unsigned short f2bf(float f) {
  unsigned u = __builtin_bit_cast(unsigned, f);
  u += 0x7fff + ((u >> 16) & 1);   // RNE
  return (unsigned short)(u >> 16);
}

__device__ __forceinline__ int region_base(int head) {
  return (head < 4) ? head * 524288 : 2097152 + (head - 4) * 262144;
}

__device__ __forceinline__ void gl_lds16(const unsigned short* g, unsigned short* l) {
  __builtin_amdgcn_global_load_lds((gp1)g, (lp3)l, 16, 0, 0);
}

__global__ __launch_bounds__(256, 4)
void prep_kernel(const float* __restrict__ K, const float* __restrict__ V,
                 unsigned short* __restrict__ Kb, unsigned short* __restrict__ Vt) {
  __shared__ unsigned short sT[64][LP];
  const int bid = blockIdx.x;
  int head, pos0, rate, off;
  if (bid < 512) { head = bid >> 7; pos0 = (bid & 127) * 64; rate = 1; off = 0; }
  else { int b = bid - 512; head = 4 + (b >> 6); pos0 = (b & 63) * 64; rate = 2; off = 1; }
  const int rb = region_base(head);
  const int tid = threadIdx.x;
  const int row = tid >> 2, dg = tid & 3;
  const long tok = (long)(pos0 + row) * rate + off;

  {
    const float* kp = K + tok * 512 + head * 64 + dg * 16;
    unsigned short tmp[16];
    #pragma unroll
    for (int i = 0; i < 4; ++i) {
      float4 f = ((const float4*)kp)[i];
      tmp[i * 4 + 0] = f2bf(f.x); tmp[i * 4 + 1] = f2bf(f.y);
      tmp[i * 4 + 2] = f2bf(f.z); tmp[i * 4 + 3] = f2bf(f.w);
    }
    const int s = row & 7;
    unsigned short* dstrow = Kb + rb + (long)(pos0 + row) * 64;
    *(int4*)(dstrow + (((2 * dg)     ^ s) * 8)) = ((int4*)tmp)[0];
    *(int4*)(dstrow + (((2 * dg + 1) ^ s) * 8)) = ((int4*)tmp)[1];
  }

  {
    const float* vp = V + tok * 512 + head * 64 + dg * 16;
    #pragma unroll
    for (int i = 0; i < 4; ++i) {
      float4 f = ((const float4*)vp)[i];
      unsigned* p = (unsigned*)&sT[row][dg * 16 + i * 4];
      p[0] = (unsigned)f2bf(f.x) | ((unsigned)f2bf(f.y) << 16);
      p[1] = (unsigned)f2bf(f.z) | ((unsigned)f2bf(f.w) << 16);
    }
  }
  __syncthreads();

  {
    // thread (wv, lane): holds V^T[d = lane][keys wv*16 .. wv*16+15] packed.
    // Frag-order dest: chunk (dt*2+h) holds, at lane2 = quad*16+l16, the 16B
    //   piece V^T[dt*16+l16][h*32 + quad*8 .. +8]  (exactly PV's A-frag).
    const int wv = tid >> 6, lane = tid & 63;
    unsigned pk[8];
    #pragma unroll
    for (int j = 0; j < 8; ++j) {
      unsigned lo = sT[wv * 16 + 2 * j][lane];
      unsigned hi = sT[wv * 16 + 2 * j + 1][lane];
      pk[j] = lo | (hi << 16);
    }
    int4 a = {(int)pk[0], (int)pk[1], (int)pk[2], (int)pk[3]};  // keys wv*16+0..7
    int4 b = {(int)pk[4], (int)pk[5], (int)pk[6], (int)pk[7]};  // keys wv*16+8..15
    const int dt = lane >> 4, l16p = lane & 15, h = wv >> 1;
    const int qa = (wv & 1) * 2, qb = qa + 1;
    unsigned short* dstc = Vt + rb + (long)pos0 * 64;
    *(int4*)(dstc + (dt * 2 + h) * 512 + (qa * 16 + l16p) * 8) = a;
    *(int4*)(dstc + (dt * 2 + h) * 512 + (qb * 16 + l16p) * 8) = b;
  }
}

__global__ __launch_bounds__(128, 2)
void attn_kernel(const float* __restrict__ Q, const unsigned short* __restrict__ Kb,
                 const unsigned short* __restrict__ Vt, const int* __restrict__ IC,
                 float* __restrict__ O, float* __restrict__ Slots) {
  __shared__ __attribute__((aligned(16))) unsigned short sK[2][4096];  // [buf][64key][64d] swz

  const int bid = blockIdx.x;
  int head, q0, seg0, mseg, rate, off, grp, chunk, slot;
  if (bid < 512) {                       // group 1: CU-balanced chunk map (R13)
    int h4 = bid & 3;
    int u = bid >> 2;                    // 0..127
    chunk = u >> 6;                      // bids <256: chunk0; >=256: chunk1
    int t = 63 - (u & 63);               // same t for the CU's two g1 blocks
    head = 4 + h4; seg0 = 0; mseg = 4096;
    rate = 2; off = 1; grp = 1;
    q0 = t * 64;
    slot = (h4 * 64 + t) * 2 + chunk;
  } else {                               // group 0: both tiles ~= c>>3 (R13)
    int cc = bid - 512;                  // 0..511
    int job = (cc & 7) | ((cc >> 8) << 3);
    int tloc = (cc & 255) >> 3;          // 0..31
    head = job & 3;
    seg0 = (job >> 2) * 2048;
    q0 = seg0 + tloc * 64; mseg = 2048;
    rate = 1; off = 0; grp = 0; chunk = 0; slot = 0;
  }
  const int rb = region_base(head);
  const bool causal = (*IC) != 0;
  const int tid = threadIdx.x, wave = tid >> 6, lane = tid & 63;   // wave in {0,1}
  const int l16 = lane & 15, quad = lane >> 4;
  const int ch0 = ((quad ^ (l16 & 7)) * 8);   // swizzled chunk offsets (shorts)
  const int ch1 = ch0 ^ 32;

  const int qloc = q0 - seg0;
  const int diagkb = qloc >> 6;
  const int nkb = causal ? diagkb + 1 : (mseg >> 6);
  const int klo = grp ? chunk * 32 : 0;
  const int khi = grp ? min(nkb, klo + 32) : nkb;
  if (klo >= khi) return;                // empty chunk (causal short tiles)

  // ---- Q B-frags for BOTH subtiles (rows wave*16+l16 and 32+wave*16+l16);
  //      scale = log2(e)/sqrt(64) so exp(s) == exp2(mfma result) ----
  const float QSCALE = 0.18033688011112042f;
  bf16x8 aQA[2], aQB[2];
  {
    #pragma unroll
    for (int st = 0; st < 2; ++st) {
      long tok = (long)(q0 + st * 32 + wave * 16 + l16) * rate + off;
      const float* qp = Q + tok * 512 + head * 64 + quad * 8;
      #pragma unroll
      for (int kc = 0; kc < 2; ++kc) {
        float4 f0 = ((const float4*)(qp + kc * 32))[0];
        float4 f1 = ((const float4*)(qp + kc * 32))[1];
        bf16x8 a;
        a[0] = (short)f2bf(f0.x * QSCALE); a[1] = (short)f2bf(f0.y * QSCALE);
        a[2] = (short)f2bf(f0.z * QSCALE); a[3] = (short)f2bf(f0.w * QSCALE);
        a[4] = (short)f2bf(f1.x * QSCALE); a[5] = (short)f2bf(f1.y * QSCALE);
        a[6] = (short)f2bf(f1.z * QSCALE); a[7] = (short)f2bf(f1.w * QSCALE);
        if (st == 0) aQA[kc] = a; else aQB[kc] = a;
      }
    }
  }

  f32x4 oaccA[4], oaccB[4];      // O^T: [d = dt*16+quad*4+r][q = l16]
  float lsumA = 0.f, lsumB = 0.f;
  #pragma unroll
  for (int dt = 0; dt < 4; ++dt) {
    oaccA[dt] = (f32x4){0.f, 0.f, 0.f, 0.f};
    oaccB[dt] = (f32x4){0.f, 0.f, 0.f, 0.f};
  }

  const unsigned short* Ksrc = Kb + rb + (long)seg0 * 64;
  const unsigned short* Vsrc = Vt + rb + (long)seg0 * 64;

  const int o0 = wave * 2048;          // shorts; each wave stages 4KB of 8KB
  const int lo = lane * 8;             // 16 B per lane
  const int qvA = qloc + wave * 16 + l16;        // subtile A query index
  const int qvB = qvA + 32;                      // subtile B query index

  auto stage_k = [&](int x, int sl) {
    const unsigned short* kt = Ksrc + (long)x * 4096;
    gl_lds16(kt + o0 + lo,        &sK[sl][o0]);
    gl_lds16(kt + o0 + 512 + lo,  &sK[sl][o0 + 512]);
    gl_lds16(kt + o0 + 1024 + lo, &sK[sl][o0 + 1024]);
    gl_lds16(kt + o0 + 1536 + lo, &sK[sl][o0 + 1536]);
  };

  struct PB { bf16x8 b0, b1; };
  // exp2 + optional mask + row-sum + pack to PV B-frag layout (per subtile)
  auto softmax_pack = [&](const f32x4* sc, int qvx, float& ls,
                          bool needMask, int kb) -> PB {
    float p[4][4];
    if (needMask) {
      #pragma unroll
      for (int c = 0; c < 4; ++c)
        #pragma unroll
        for (int r = 0; r < 4; ++r) {
          float e = __builtin_amdgcn_exp2f(sc[c][r]);
          if (kb * 64 + c * 16 + quad * 4 + r > qvx) e = 0.f;
          p[c][r] = e;
        }
    } else {
      #pragma unroll
      for (int c = 0; c < 4; ++c)
        #pragma unroll
        for (int r = 0; r < 4; ++r)
          p[c][r] = __builtin_amdgcn_exp2f(sc[c][r]);
    }

    ls += (((p[0][0] + p[0][1]) + (p[0][2] + p[0][3])) +
           ((p[1][0] + p[1][1]) + (p[1][2] + p[1][3]))) +
          (((p[2][0] + p[2][1]) + (p[2][2] + p[2][3])) +
           ((p[3][0] + p[3][1]) + (p[3][2] + p[3][3])));

    unsigned W00, W01, W10, W11, W20, W21, W30, W31;
    asm("v_cvt_pk_bf16_f32 %0, %1, %2" : "=v"(W00) : "v"(p[0][0]), "v"(p[0][1]));
    asm("v_cvt_pk_bf16_f32 %0, %1, %2" : "=v"(W01) : "v"(p[0][2]), "v"(p[0][3]));
    asm("v_cvt_pk_bf16_f32 %0, %1, %2" : "=v"(W10) : "v"(p[1][0]), "v"(p[1][1]));
    asm("v_cvt_pk_bf16_f32 %0, %1, %2" : "=v"(W11) : "v"(p[1][2]), "v"(p[1][3]));
    asm("v_cvt_pk_bf16_f32 %0, %1, %2" : "=v"(W20) : "v"(p[2][0]), "v"(p[2][1]));
    asm("v_cvt_pk_bf16_f32 %0, %1, %2" : "=v"(W21) : "v"(p[2][2]), "v"(p[2][3]));
    asm("v_cvt_pk_bf16_f32 %0, %1, %2" : "=v"(W30) : "v"(p[3][0]), "v"(p[3][1]));
    asm("v_cvt_pk_bf16_f32 %0, %1, %2" : "=v"(W31) : "v"(p[3][2]), "v"(p[3][3]));

    unsigned R0 = W00, R2 = W10;
    asm("v_permlane32_swap_b32 %0, %1" : "+v"(R0), "+v"(R2));
    asm("v_permlane16_swap_b32 %0, %1" : "+v"(R0), "+v"(R2));
    unsigned R1 = W01, R3 = W11;
    asm("v_permlane32_swap_b32 %0, %1" : "+v"(R1), "+v"(R3));
    asm("v_permlane16_swap_b32 %0, %1" : "+v"(R1), "+v"(R3));
    unsigned R4 = W20, R6 = W30;
    asm("v_permlane32_swap_b32 %0, %1" : "+v"(R4), "+v"(R6));
    asm("v_permlane16_swap_b32 %0, %1" : "+v"(R4), "+v"(R6));
    unsigned R5 = W21, R7 = W31;
    asm("v_permlane32_swap_b32 %0, %1" : "+v"(R5), "+v"(R7));
    asm("v_permlane16_swap_b32 %0, %1" : "+v"(R5), "+v"(R7));
    u32x4 t0 = {R0, R1, R2, R3};
    u32x4 t1 = {R4, R5, R6, R7};
    PB pb;
    pb.b0 = __builtin_bit_cast(bf16x8, t0);   // keys  0..31 for q=l16
    pb.b1 = __builtin_bit_cast(bf16x8, t1);   // keys 32..63
    return pb;
  };

  // ---- prologue: K(klo) into sK[0] ----
  stage_k(klo, 0);

  for (int kb = klo; kb < khi; ++kb) {
    const int cur = (kb - klo) & 1;
    __syncthreads();   // K(kb) staged & visible; sK[cur^1] free

    // V(kb) frag loads: global->reg, shared by BOTH subtiles.
    int4 vr[8];
    {
      const int4* vt = (const int4*)(Vsrc + (long)kb * 4096);
      #pragma unroll
      for (int c = 0; c < 8; ++c) vr[c] = vt[c * 64 + lane];
    }
    if (kb + 1 < khi) stage_k(kb + 1, cur ^ 1);

    // ---- S^T = K Q^T for both subtiles; kr frags read ONCE ----
    f32x4 scA[4], scB[4];
    #pragma unroll
    for (int c = 0; c < 4; ++c) {
      const unsigned short* krow = &sK[cur][(c * 16 + l16) * 64];
      bf16x8 b0 = *(const bf16x8*)(krow + ch0);
      bf16x8 b1 = *(const bf16x8*)(krow + ch1);
      f32x4 zA = (f32x4){0.f, 0.f, 0.f, 0.f};
      zA = __builtin_amdgcn_mfma_f32_16x16x32_bf16(b0, aQA[0], zA, 0, 0, 0);
      zA = __builtin_amdgcn_mfma_f32_16x16x32_bf16(b1, aQA[1], zA, 0, 0, 0);
      scA[c] = zA;
      f32x4 zB = (f32x4){0.f, 0.f, 0.f, 0.f};
      zB = __builtin_amdgcn_mfma_f32_16x16x32_bf16(b0, aQB[0], zB, 0, 0, 0);
      zB = __builtin_amdgcn_mfma_f32_16x16x32_bf16(b1, aQB[1], zB, 0, 0, 0);
      scB[c] = zB;
    }

    // ---- softmax + pack, two independent chains (R15 uniform branch) ----
    const bool needMask = causal && (kb == diagkb);
    PB pbA = softmax_pack(scA, qvA, lsumA, needMask, kb);
    PB pbB = softmax_pack(scB, qvB, lsumB, needMask, kb);

    // ---- O^T += V^T P^T, V frags shared ----
    #pragma unroll
    for (int dt = 0; dt < 4; ++dt) {
      bf16x8 v0 = __builtin_bit_cast(bf16x8, vr[dt * 2]);
      bf16x8 v1 = __builtin_bit_cast(bf16x8, vr[dt * 2 + 1]);
      oaccA[dt] = __builtin_amdgcn_mfma_f32_16x16x32_bf16(v0, pbA.b0, oaccA[dt], 0, 0, 0);
      oaccA[dt] = __builtin_amdgcn_mfma_f32_16x16x32_bf16(v1, pbA.b1, oaccA[dt], 0, 0, 0);
      oaccB[dt] = __builtin_amdgcn_mfma_f32_16x16x32_bf16(v0, pbB.b0, oaccB[dt], 0, 0, 0);
      oaccB[dt] = __builtin_amdgcn_mfma_f32_16x16x32_bf16(v1, pbB.b1, oaccB[dt], 0, 0, 0);
    }
  }

  // ---- cross-quad reduce + epilogues (per subtile) ----
  float ltotA = lsumA;
  ltotA += __shfl_xor(ltotA, 16);
  ltotA += __shfl_xor(ltotA, 32);
  float ltotB = lsumB;
  ltotB += __shfl_xor(ltotB, 16);
  ltotB += __shfl_xor(ltotB, 32);

  #pragma unroll
  for (int st = 0; st < 2; ++st) {
    const int qrow = st * 32 + wave * 16 + l16;
    const float ltot = st ? ltotB : ltotA;
    const f32x4* oacc = st ? oaccB : oaccA;
    if (grp == 1) {
      float* S = Slots + (long)slot * 4160;
      #pragma unroll
      for (int dt = 0; dt < 4; ++dt)
        #pragma unroll
        for (int r = 0; r < 4; ++r)
          S[qrow * 64 + dt * 16 + quad * 4 + r] = oacc[dt][r];
      if (quad == 0) S[4096 + qrow] = ltot;
    } else {
      const int tq = q0 + qrow;                // g0: rate=1, off=0
      const float inv = 1.0f / ltot;
      float* dst = O + (long)tq * 512 + head * 64 + quad * 4;
      #pragma unroll
      for (int dt = 0; dt < 4; ++dt)
        #pragma unroll
        for (int r = 0; r < 4; ++r)
          dst[dt * 16 + r] = oacc[dt][r] * inv;
    }
  }
}

__global__ __launch_bounds__(256, 4)
void combine_kernel(const float* __restrict__ Slots, const int* __restrict__ IC,
                    float* __restrict__ O) {
  const int b = blockIdx.x;            // 256 = 4 heads x 64 tiles
  const int h4 = b >> 6, t = b & 63;
  const bool causal = (*IC) != 0;
  const int nkb = causal ? t + 1 : 64;
  const int nc = (nkb > 32) ? 2 : 1;
  const float* s0 = Slots + (long)((h4 * 64 + t) * 2) * 4160;
  const int tid = threadIdx.x;
  const int row = tid >> 2, dq = (tid & 3) * 16;

  float4 acc[4];
  const float4* p0 = (const float4*)(s0 + row * 64 + dq);
  #pragma unroll
  for (int i = 0; i < 4; ++i) acc[i] = p0[i];
  float l = s0[4096 + row];
  if (nc == 2) {
    const float* s1 = s0 + 4160;
    const float4* p1 = (const float4*)(s1 + row * 64 + dq);
    #pragma unroll
    for (int i = 0; i < 4; ++i) {
      float4 v = p1[i];
      acc[i].x += v.x; acc[i].y += v.y; acc[i].z += v.z; acc[i].w += v.w;
    }
    l += s1[4096 + row];
  }
  const float inv = 1.0f / l;
  const long tok = (long)(t * 64 + row) * 2 + 1;     // odd (dilated) token
  float* dst = O + tok * 512 + (4 + h4) * 64 + dq;
  #pragma unroll
  for (int i = 0; i < 4; ++i) {
    float4 o = {acc[i].x * inv, acc[i].y * inv, acc[i].z * inv, acc[i].w * inv};
    ((float4*)dst)[i] = o;
  }
  float* dste = O + (tok - 1) * 512 + (4 + h4) * 64 + dq;   // paired even token
  const float4 z = {0.f, 0.f, 0.f, 0.f};
  #pragma unroll
  for (int i = 0; i < 4; ++i) ((float4*)dste)[i] = z;
}

extern "C" void kernel_launch(void* const* d_in, const int* in_sizes, int n_in,
                              void* d_out, int out_size, void* d_ws, size_t ws_size,
                              hipStream_t stream) {
  const float* q = (const float*)d_in[0];
  const float* k = (const float*)d_in[1];
  const float* v = (const float*)d_in[2];
  const int* ic = (const int*)d_in[3];
  unsigned short* Kb = (unsigned short*)d_ws;                 // 6 MB
  unsigned short* Vt = Kb + 3145728;                          // 6 MB (frag order)
  float* Slots = (float*)((char*)d_ws + 12582912);            // 512 x 4160 fl = 8.2 MB
  prep_kernel<<<dim3(768), dim3(256), 0, stream>>>(k, v, Kb, Vt);
  attn_kernel<<<dim3(1024), dim3(128), 0, stream>>>(q, Kb, Vt, ic, (float*)d_out, Slots);
  combine_kernel<<<dim3(256), dim3(256), 0, stream>>>(Slots, ic, (float*)d_out);
}

// Round 14
// 127.406 us; speedup vs baseline: 1.0781x; 1.0781x over previous
//
#include <hip/hip_runtime.h>

// Dilated attention, [1, 8192, 8, 64] fp32 in/out.
// Group 0 (heads 0-3): 4 segments x 2048 tokens, rate 1, dense causal.
// Group 1 (heads 4-7): 1 segment, odd tokens only (4096 dilated), evens = 0.
//
// ===== R25/R26: the empirical optimum (R18/R23 config, 128.46 us). =====
// (R26 = byte-identical resubmit; R25's bench died on container acquisition,
//  same infra failure as R9. This exact source passed at 128.46us in R11.)
// prep:    gather dilated tokens -> bf16 ws:
//            Kb[region][pos][64d]        (chunk-XOR-swizzled rows, for LDS)
//            Vt[region][kb][8chunk][64lane][8] (MFMA-frag order, reg-direct)
// attn:    64-query blocks, 4 waves split Q. K double-buffered in 16KB LDS via
//          async global_load_lds, ONE __syncthreads/iter (implicit 1-iter
//          prefetch — the only latency-hiding scheme that ever worked here).
//          V loaded global->register per wave (R18, frag order). No-max
//          softmax; exp2 with log2e folded into Q scale. S^T operand swap
//          (R16): P in-register via cvt_pk_bf16 + permlane swaps.
//          Group-1 tiles split into 2 K-chunks -> unnormalized partials to ws.
// combine: per group-1 tile, sum <=2 slots, divide, write odd tokens,
//          zero paired even tokens.
// Dispatch (R13): CU c gets g1 chunk0+chunk1 of tile 63-(c>>2) plus two g0
//          tiles tloc=c>>3 -> ~66 iters/CU; structurally 2 LONG blocks/CU.
//
// Complete experiment ledger (what NOT to retry):
// R5:  launch_bounds(256,8) -> VGPR spill catastrophe; keep (256,2).
// R6:  SCATTERED per-wave 16B frag reads = 805 MB L2 traffic; frag-ORDER
//      contiguous dwordx4 reads (V here) are coalesced — different animal.
// R7:  unswizzled ws rows -> 1.34e7 LDS conflict cycles; keep K swizzle.
// R10: fatter Q-blocks at fewer blocks/CU regress; keep 64-q blocks.
// R12: change ONE variable per round.
// R14/R19: finer chunking + grid oversubscription (at 40KB AND at 16KB LDS):
//      occupancy never moves (~20%), +30% attn from per-block overhead.
//      Residency/concurrency is NOT a usable lever on this kernel.
// R15 WIN: uniform-branch causal mask: attn 49.4->45.5us.
// R16 WIN: S^T swap, P in-register (cvt_pk+permlane), sP deleted:
//      total 135.5->128.9; attn ~45.5->~39.
// R17: counted-vmcnt ring-3 LDS pipeline: neutral. Barrier drain not the stall.
// R18 WIN (this config): V global->reg, sV deleted, LDS 40->16KB:
//      total 128.3. LDS BW not the stall either, but frees LDS + simplifies.
// R20: paired k-blocks (2/barrier interval): attn 50us. Longer co-stalls.
// R21: barrier-free (K also global->reg): attn 46us — compiler sinks loads
//      to uses (VGPR=52), exposing full L2 latency per iter; no prefetch.
// R22: forced register double-buffer on R21: attn 61us, VGPR 96, occ 12% —
//      compiler half-serializes the buffers; worse than both R18 and R21.
// R24: dual-subtile 128-thread waves: attn 46us, VGPR 76 — compiler again
//      refuses to keep the 2nd chain's state live (serializes B behind A),
//      and waves/CU halve 8->4. Same failure mechanism as R22.
// Conclusion (structural): per block-iter wall ~1418cy; issue ~370cy spread
//      across pipes (VALU 25%, MFMA 15%, LDS ~20%; none >25%); the rest is
//      dependency stall. Eight restructures (R14,R17,R19,R20,R21,R22,R24 +
//      oversub) all fail because regalloc caps live pipeline state (~100
//      VGPR), counted-vmcnt conflicts with barrier semantics, and barrier
//      removal loses prefetch. Only serial-chain shortening ever won
//      (R15,R16). attn floor ~39us in this structure; ~88us of dur_us is
//      attn-independent (harness poison + prep + combine).

#define LP 72

typedef __attribute__((ext_vector_type(8))) short bf16x8;
typedef __attribute__((ext_vector_type(4))) float f32x4;
typedef __attribute__((ext_vector_type(4))) unsigned u32x4;
typedef const unsigned int __attribute__((address_space(1)))* gp1;
typedef unsigned int __attribute__((address_space(3)))* lp3;

__device__ __forceinline__ unsigned short f2bf(float f) {
  unsigned u = __builtin_bit_cast(unsigned, f);
  u += 0x7fff + ((u >> 16) & 1);   // RNE
  return (unsigned short)(u >> 16);
}

__device__ __forceinline__ int region_base(int head) {
  return (head < 4) ? head * 524288 : 2097152 + (head - 4) * 262144;
}

__device__ __forceinline__ void gl_lds16(const unsigned short* g, unsigned short* l) {
  __builtin_amdgcn_global_load_lds((gp1)g, (lp3)l, 16, 0, 0);
}

__global__ __launch_bounds__(256, 4)
void prep_kernel(const float* __restrict__ K, const float* __restrict__ V,
                 unsigned short* __restrict__ Kb, unsigned short* __restrict__ Vt) {
  __shared__ unsigned short sT[64][LP];
  const int bid = blockIdx.x;
  int head, pos0, rate, off;
  if (bid < 512) { head = bid >> 7; pos0 = (bid & 127) * 64; rate = 1; off = 0; }
  else { int b = bid - 512; head = 4 + (b >> 6); pos0 = (b & 63) * 64; rate = 2; off = 1; }
  const int rb = region_base(head);
  const int tid = threadIdx.x;
  const int row = tid >> 2, dg = tid & 3;
  const long tok = (long)(pos0 + row) * rate + off;

  {
    const float* kp = K + tok * 512 + head * 64 + dg * 16;
    unsigned short tmp[16];
    #pragma unroll
    for (int i = 0; i < 4; ++i) {
      float4 f = ((const float4*)kp)[i];
      tmp[i * 4 + 0] = f2bf(f.x); tmp[i * 4 + 1] = f2bf(f.y);
      tmp[i * 4 + 2] = f2bf(f.z); tmp[i * 4 + 3] = f2bf(f.w);
    }
    const int s = row & 7;
    unsigned short* dstrow = Kb + rb + (long)(pos0 + row) * 64;
    *(int4*)(dstrow + (((2 * dg)     ^ s) * 8)) = ((int4*)tmp)[0];
    *(int4*)(dstrow + (((2 * dg + 1) ^ s) * 8)) = ((int4*)tmp)[1];
  }

  {
    const float* vp = V + tok * 512 + head * 64 + dg * 16;
    #pragma unroll
    for (int i = 0; i < 4; ++i) {
      float4 f = ((const float4*)vp)[i];
      unsigned* p = (unsigned*)&sT[row][dg * 16 + i * 4];
      p[0] = (unsigned)f2bf(f.x) | ((unsigned)f2bf(f.y) << 16);
      p[1] = (unsigned)f2bf(f.z) | ((unsigned)f2bf(f.w) << 16);
    }
  }
  __syncthreads();

  {
    // thread (wv, lane): holds V^T[d = lane][keys wv*16 .. wv*16+15] packed.
    // Frag-order dest: chunk (dt*2+h) holds, at lane2 = quad*16+l16, the 16B
    //   piece V^T[dt*16+l16][h*32 + quad*8 .. +8]  (exactly PV's A-frag).
    const int wv = tid >> 6, lane = tid & 63;
    unsigned pk[8];
    #pragma unroll
    for (int j = 0; j < 8; ++j) {
      unsigned lo = sT[wv * 16 + 2 * j][lane];
      unsigned hi = sT[wv * 16 + 2 * j + 1][lane];
      pk[j] = lo | (hi << 16);
    }
    int4 a = {(int)pk[0], (int)pk[1], (int)pk[2], (int)pk[3]};  // keys wv*16+0..7
    int4 b = {(int)pk[4], (int)pk[5], (int)pk[6], (int)pk[7]};  // keys wv*16+8..15
    const int dt = lane >> 4, l16p = lane & 15, h = wv >> 1;
    const int qa = (wv & 1) * 2, qb = qa + 1;
    unsigned short* dstc = Vt + rb + (long)pos0 * 64;
    *(int4*)(dstc + (dt * 2 + h) * 512 + (qa * 16 + l16p) * 8) = a;
    *(int4*)(dstc + (dt * 2 + h) * 512 + (qb * 16 + l16p) * 8) = b;
  }
}

__global__ __launch_bounds__(256, 2)
void attn_kernel(const float* __restrict__ Q, const unsigned short* __restrict__ Kb,
                 const unsigned short* __restrict__ Vt, const int* __restrict__ IC,
                 float* __restrict__ O, float* __restrict__ Slots) {
  __shared__ __attribute__((aligned(16))) unsigned short sK[2][4096];  // [buf][64key][64d] swz

  const int bid = blockIdx.x;
  int head, q0, seg0, mseg, rate, off, grp, chunk, slot;
  if (bid < 512) {                       // group 1: CU-balanced chunk map (R13)
    int h4 = bid & 3;
    int u = bid >> 2;                    // 0..127
    chunk = u >> 6;                      // bids <256: chunk0; >=256: chunk1
    int t = 63 - (u & 63);               // same t for the CU's two g1 blocks
    head = 4 + h4; seg0 = 0; mseg = 4096;
    rate = 2; off = 1; grp = 1;
    q0 = t * 64;
    slot = (h4 * 64 + t) * 2 + chunk;
  } else {                               // group 0: both tiles ~= c>>3 (R13)
    int cc = bid - 512;                  // 0..511
    int job = (cc & 7) | ((cc >> 8) << 3);
    int tloc = (cc & 255) >> 3;          // 0..31
    head = job & 3;
    seg0 = (job >> 2) * 2048;
    q0 = seg0 + tloc * 64; mseg = 2048;
    rate = 1; off = 0; grp = 0; chunk = 0; slot = 0;
  }
  const int rb = region_base(head);
  const bool causal = (*IC) != 0;
  const int tid = threadIdx.x, wave = tid >> 6, lane = tid & 63;
  const int l16 = lane & 15, quad = lane >> 4;
  const int ch0 = ((quad ^ (l16 & 7)) * 8);   // swizzled chunk offsets (shorts)
  const int ch1 = ch0 ^ 32;

  const int qloc = q0 - seg0;
  const int diagkb = qloc >> 6;
  const int nkb = causal ? diagkb + 1 : (mseg >> 6);
  const int klo = grp ? chunk * 32 : 0;
  const int khi = grp ? min(nkb, klo + 32) : nkb;
  if (klo >= khi) return;                // empty chunk (causal short tiles)

  // ---- Q B-frags (wave's 16 q-cols); scale = log2(e)/sqrt(64) so that
  //      exp(s) == exp2(mfma result) — saves a v_mul per exp ----
  const float QSCALE = 0.18033688011112042f;
  bf16x8 aQ[2];
  {
    long tok = (long)(q0 + wave * 16 + l16) * rate + off;
    const float* qp = Q + tok * 512 + head * 64 + quad * 8;
    #pragma unroll
    for (int kc = 0; kc < 2; ++kc) {
      float4 f0 = ((const float4*)(qp + kc * 32))[0];
      float4 f1 = ((const float4*)(qp + kc * 32))[1];
      bf16x8 a;
      a[0] = (short)f2bf(f0.x * QSCALE); a[1] = (short)f2bf(f0.y * QSCALE);
      a[2] = (short)f2bf(f0.z * QSCALE); a[3] = (short)f2bf(f0.w * QSCALE);
      a[4] = (short)f2bf(f1.x * QSCALE); a[5] = (short)f2bf(f1.y * QSCALE);
      a[6] = (short)f2bf(f1.z * QSCALE); a[7] = (short)f2bf(f1.w * QSCALE);
      aQ[kc] = a;
    }
  }

  f32x4 oacc[4];                 // O^T: [d = dt*16+quad*4+r][q = l16]
  float lsum = 0.f;              // per-lane partial row-sum for q = l16
  #pragma unroll
  for (int dt = 0; dt < 4; ++dt) oacc[dt] = (f32x4){0.f, 0.f, 0.f, 0.f};

  const unsigned short* Ksrc = Kb + rb + (long)seg0 * 64;
  const unsigned short* Vsrc = Vt + rb + (long)seg0 * 64;

  const int o0 = wave * 1024;          // shorts
  const int lo = lane * 8;             // 16 B per lane
  const int qv = qloc + wave * 16 + l16;   // this lane's query (local) index

  auto stage_k = [&](int x, int sl) {
    const unsigned short* kt = Ksrc + (long)x * 4096;
    gl_lds16(kt + o0 + lo,       &sK[sl][o0]);
    gl_lds16(kt + o0 + 512 + lo, &sK[sl][o0 + 512]);
  };

  // ---- prologue: K(klo) into sK[0] ----
  stage_k(klo, 0);

  for (int kb = klo; kb < khi; ++kb) {
    const int cur = (kb - klo) & 1;
    __syncthreads();   // K(kb) staged & visible; sK[cur^1] free

    // V(kb) frag loads: global->reg, coalesced 1KB/instr, per-wave private.
    // Issued first so the QK/exp/pack phase covers their L1/L2 latency.
    int4 vr[8];
    {
      const int4* vt = (const int4*)(Vsrc + (long)kb * 4096);
      #pragma unroll
      for (int c = 0; c < 8; ++c) vr[c] = vt[c * 64 + lane];
    }
    if (kb + 1 < khi) stage_k(kb + 1, cur ^ 1);

    // ---- S^T = K Q^T (swapped operands: lane holds S^T[key][q=l16]) ----
    f32x4 sc[4];
    #pragma unroll
    for (int c = 0; c < 4; ++c) {
      const unsigned short* krow = &sK[cur][(c * 16 + l16) * 64];
      bf16x8 b0 = *(const bf16x8*)(krow + ch0);
      bf16x8 b1 = *(const bf16x8*)(krow + ch1);
      f32x4 z = (f32x4){0.f, 0.f, 0.f, 0.f};
      z = __builtin_amdgcn_mfma_f32_16x16x32_bf16(b0, aQ[0], z, 0, 0, 0);
      z = __builtin_amdgcn_mfma_f32_16x16x32_bf16(b1, aQ[1], z, 0, 0, 0);
      sc[c] = z;   // sc[c][r] = S^T[key = kb*64 + c*16 + quad*4 + r][q = l16]
    }

    // ---- P^T = exp2(S^T) in registers (R15 uniform mask branch) ----
    float p[4][4];
    if (causal && (kb == diagkb)) {
      #pragma unroll
      for (int c = 0; c < 4; ++c)
        #pragma unroll
        for (int r = 0; r < 4; ++r) {
          float e = __builtin_amdgcn_exp2f(sc[c][r]);
          if (kb * 64 + c * 16 + quad * 4 + r > qv) e = 0.f;
          p[c][r] = e;
        }
    } else {
      #pragma unroll
      for (int c = 0; c < 4; ++c)
        #pragma unroll
        for (int r = 0; r < 4; ++r)
          p[c][r] = __builtin_amdgcn_exp2f(sc[c][r]);
    }

    // ---- partial row-sum ----
    lsum += (((p[0][0] + p[0][1]) + (p[0][2] + p[0][3])) +
             ((p[1][0] + p[1][1]) + (p[1][2] + p[1][3]))) +
            (((p[2][0] + p[2][1]) + (p[2][2] + p[2][3])) +
             ((p[3][0] + p[3][1]) + (p[3][2] + p[3][3])));

    // ---- pack P^T pairs to bf16 (key 2p low, 2p+1 high) ----
    unsigned W00, W01, W10, W11, W20, W21, W30, W31;
    asm("v_cvt_pk_bf16_f32 %0, %1, %2" : "=v"(W00) : "v"(p[0][0]), "v"(p[0][1]));
    asm("v_cvt_pk_bf16_f32 %0, %1, %2" : "=v"(W01) : "v"(p[0][2]), "v"(p[0][3]));
    asm("v_cvt_pk_bf16_f32 %0, %1, %2" : "=v"(W10) : "v"(p[1][0]), "v"(p[1][1]));
    asm("v_cvt_pk_bf16_f32 %0, %1, %2" : "=v"(W11) : "v"(p[1][2]), "v"(p[1][3]));
    asm("v_cvt_pk_bf16_f32 %0, %1, %2" : "=v"(W20) : "v"(p[2][0]), "v"(p[2][1]));
    asm("v_cvt_pk_bf16_f32 %0, %1, %2" : "=v"(W21) : "v"(p[2][2]), "v"(p[2][3]));
    asm("v_cvt_pk_bf16_f32 %0, %1, %2" : "=v"(W30) : "v"(p[3][0]), "v"(p[3][1]));
    asm("v_cvt_pk_bf16_f32 %0, %1, %2" : "=v"(W31) : "v"(p[3][2]), "v"(p[3][3]));

    // ---- in-register redistribution to PV B-frag layout ----
    unsigned R0 = W00, R2 = W10;
    asm("v_permlane32_swap_b32 %0, %1" : "+v"(R0), "+v"(R2));
    asm("v_permlane16_swap_b32 %0, %1" : "+v"(R0), "+v"(R2));
    unsigned R1 = W01, R3 = W11;
    asm("v_permlane32_swap_b32 %0, %1" : "+v"(R1), "+v"(R3));
    asm("v_permlane16_swap_b32 %0, %1" : "+v"(R1), "+v"(R3));
    unsigned R4 = W20, R6 = W30;
    asm("v_permlane32_swap_b32 %0, %1" : "+v"(R4), "+v"(R6));
    asm("v_permlane16_swap_b32 %0, %1" : "+v"(R4), "+v"(R6));
    unsigned R5 = W21, R7 = W31;
    asm("v_permlane32_swap_b32 %0, %1" : "+v"(R5), "+v"(R7));
    asm("v_permlane16_swap_b32 %0, %1" : "+v"(R5), "+v"(R7));
    u32x4 t0 = {R0, R1, R2, R3};
    u32x4 t1 = {R4, R5, R6, R7};
    bf16x8 pB0 = __builtin_bit_cast(bf16x8, t0);   // keys  0..31 for q=l16
    bf16x8 pB1 = __builtin_bit_cast(bf16x8, t1);   // keys 32..63

    // ---- O^T += V^T P^T (V frags from registers) ----
    #pragma unroll
    for (int dt = 0; dt < 4; ++dt) {
      bf16x8 v0 = __builtin_bit_cast(bf16x8, vr[dt * 2]);
      bf16x8 v1 = __builtin_bit_cast(bf16x8, vr[dt * 2 + 1]);
      oacc[dt] = __builtin_amdgcn_mfma_f32_16x16x32_bf16(v0, pB0, oacc[dt], 0, 0, 0);
      oacc[dt] = __builtin_amdgcn_mfma_f32_16x16x32_bf16(v1, pB1, oacc[dt], 0, 0, 0);
    }
  }

  // ---- cross-quad reduce: total row-sum for q = l16, replicated ----
  float ltot = lsum;
  ltot += __shfl_xor(ltot, 16);
  ltot += __shfl_xor(ltot, 32);

  if (grp == 1) {
    // ---- partial slot store (unnormalized); layout unchanged [q][d] ----
    float* S = Slots + (long)slot * 4160;
    const int qrow = wave * 16 + l16;
    #pragma unroll
    for (int dt = 0; dt < 4; ++dt)
      #pragma unroll
      for (int r = 0; r < 4; ++r)
        S[qrow * 64 + dt * 16 + quad * 4 + r] = oacc[dt][r];
    if (quad == 0) S[4096 + qrow] = ltot;
  } else {
    // ---- direct epilogue: divide + store (transposed scatter; L2 absorbs) ----
    const int tq = q0 + wave * 16 + l16;     // g0: rate=1, off=0
    const float inv = 1.0f / ltot;
    float* dst = O + (long)tq * 512 + head * 64 + quad * 4;
    #pragma unroll
    for (int dt = 0; dt < 4; ++dt)
      #pragma unroll
      for (int r = 0; r < 4; ++r)
        dst[dt * 16 + r] = oacc[dt][r] * inv;
  }
}

__global__ __launch_bounds__(256, 4)
void combine_kernel(const float* __restrict__ Slots, const int* __restrict__ IC,
                    float* __restrict__ O) {
  const int b = blockIdx.x;            // 256 = 4 heads x 64 tiles
  const int h4 = b >> 6, t = b & 63;
  const bool causal = (*IC) != 0;
  const int nkb = causal ? t + 1 : 64;
  const int nc = (nkb > 32) ? 2 : 1;
  const float* s0 = Slots + (long)((h4 * 64 + t) * 2) * 4160;
  const int tid = threadIdx.x;
  const int row = tid >> 2, dq = (tid & 3) * 16;

  float4 acc[4];
  const float4* p0 = (const float4*)(s0 + row * 64 + dq);
  #pragma unroll
  for (int i = 0; i < 4; ++i) acc[i] = p0[i];
  float l = s0[4096 + row];
  if (nc == 2) {
    const float* s1 = s0 + 4160;
    const float4* p1 = (const float4*)(s1 + row * 64 + dq);
    #pragma unroll
    for (int i = 0; i < 4; ++i) {
      float4 v = p1[i];
      acc[i].x += v.x; acc[i].y += v.y; acc[i].z += v.z; acc[i].w += v.w;
    }
    l += s1[4096 + row];
  }
  const float inv = 1.0f / l;
  const long tok = (long)(t * 64 + row) * 2 + 1;     // odd (dilated) token
  float* dst = O + tok * 512 + (4 + h4) * 64 + dq;
  #pragma unroll
  for (int i = 0; i < 4; ++i) {
    float4 o = {acc[i].x * inv, acc[i].y * inv, acc[i].z * inv, acc[i].w * inv};
    ((float4*)dst)[i] = o;
  }
  float* dste = O + (tok - 1) * 512 + (4 + h4) * 64 + dq;   // paired even token
  const float4 z = {0.f, 0.f, 0.f, 0.f};
  #pragma unroll
  for (int i = 0; i < 4; ++i) ((float4*)dste)[i] = z;
}

extern "C" void kernel_launch(void* const* d_in, const int* in_sizes, int n_in,
                              void* d_out, int out_size, void* d_ws, size_t ws_size,
                              hipStream_t stream) {
  const float* q = (const float*)d_in[0];
  const float* k = (const float*)d_in[1];
  const float* v = (const float*)d_in[2];
  const int* ic = (const int*)d_in[3];
  unsigned short* Kb = (unsigned short*)d_ws;                 // 6 MB
  unsigned short* Vt = Kb + 3145728;                          // 6 MB (frag order)
  float* Slots = (float*)((char*)d_ws + 12582912);            // 512 x 4160 fl = 8.2 MB
  prep_kernel<<<dim3(768), dim3(256), 0, stream>>>(k, v, Kb, Vt);
  attn_kernel<<<dim3(1024), dim3(256), 0, stream>>>(q, Kb, Vt, ic, (float*)d_out, Slots);
  combine_kernel<<<dim3(256), dim3(256), 0, stream>>>(Slots, ic, (float*)d_out);
}